// Round 6
// baseline (1757.570 us; speedup 1.0000x reference)
//
#include <hip/hip_runtime.h>
#include <math.h>

typedef _Float16 f16;
typedef __attribute__((ext_vector_type(8))) _Float16 half8;
typedef __attribute__((ext_vector_type(4))) _Float16 half4;
typedef __attribute__((ext_vector_type(4))) float floatx4;

#define NB 8192

// ======================= weight conversion =======================
// Linear (swz==0): dst[u][n][k] = src[u*K*N + k*N + n] * scale
// Swizzled (swz==GM): dst piece (n, g') holds k-group g = g'^(n&swz), so that a
// linear lane-order global_load_lds lands XOR-swizzled data in LDS.
struct ConvJob { const float* src; f16* dst; int K; int N; int ucount; float scale; int swz; };
struct ConvJobs { ConvJob j[28]; };

__global__ void convert_w(ConvJobs JJ) {
    ConvJob jb = JJ.j[blockIdx.z];
    int u = blockIdx.x;
    if (u >= jb.ucount) return;
    __shared__ f16 tile[128 * 136];
    const int K = jb.K, N = jb.N;
    const int npad = N + 8;
    const int nsh = (N == 128) ? 7 : 6;
    const int ksh = (K == 128) ? 7 : 6;
    const float* src = jb.src + (size_t)u * K * N;
    for (int idx = threadIdx.x; idx < K * N; idx += 256) {
        int k = idx >> nsh, n = idx & (N - 1);
        tile[k * npad + n] = (f16)(src[idx] * jb.scale);
    }
    __syncthreads();
    f16* dst = jb.dst + (size_t)u * N * K;
    for (int idx = threadIdx.x; idx < N * K; idx += 256) {
        int n = idx >> ksh, rem = idx & (K - 1);
        int g2 = rem >> 3, jj = rem & 7;
        int g = jb.swz ? (g2 ^ (n & jb.swz)) : g2;
        int k = g * 8 + jj;
        dst[idx] = tile[k * npad + n];
    }
}

// ======================= x -> planar f16 =======================
__global__ void x_to_planes(const float* __restrict__ x, f16* s_p, f16* v0, f16* v1, f16* v2) {
    int t = blockIdx.x * 256 + threadIdx.x;
    if (t >= NB * 64) return;
    int b = t >> 6, u = t & 63;
    const float* xr = x + (size_t)b * 256;
    s_p[t] = (f16)xr[u];
    v0[t] = (f16)xr[64 + 3 * u + 0];
    v1[t] = (f16)xr[64 + 3 * u + 1];
    v2[t] = (f16)xr[64 + 3 * u + 2];
}

// ======================= tensor-product unit (v3 + residency=5) =======================
// out[b,w] = sum_u p[b,u] * sum_v q[b,v] * Wt[u][w][v]
// W staged global->LDS via global_load_lds; pre-swizzled so linear DMA lands
// conflict-free; 2-slab LDS + one __syncthreads per u-step (compile-time slab
// index). launch_bounds(256,5): 5 blocks/CU — 5*32KB = full 160KB LDS, grid
// 1280 = exactly 5/CU = one balanced generation; 5 interleaved barrier chains
// hide each other's stalls.
struct TpJob { const f16* p; const f16* q; const f16* w; float* out; int pstride; int qstride; };
struct TpJobs { TpJob j[10]; };

template <int M>
__launch_bounds__(256, 5)
__global__ void tp_unit(TpJobs JJ) {
    TpJob jb = JJ.j[blockIdx.z];
    constexpr int KC = M / 32;            // 32-wide k chunks
    constexpr int GM = M / 8 - 1;         // swizzle key mask
    constexpr int SLABH = 64 * M;         // halfs per col-half slab
    constexpr int PIECES = SLABH / 8;     // 16B pieces per slab
    constexpr int IPW = PIECES / 256;     // glds instrs per thread per stage
    constexpr int SLABFULL = 128 * M;     // halfs per full (128-col) slab
    __shared__ f16 w_lds[2][SLABH];
    const int tid = threadIdx.x, lane = tid & 63, wave = tid >> 6;
    const int wm = wave & 1, wn = wave >> 1;
    const int l15 = lane & 15, quad = lane >> 4;
    const int rowBase = blockIdx.x * 128;
    const int colBase = blockIdx.y * 64;

    // Q fragments: register-resident (A-operand source)
    half8 qf[4][KC];
    int prow[4];
    #pragma unroll
    for (int t = 0; t < 4; t++) {
        int row = rowBase + wm * 64 + t * 16 + l15;
        prow[t] = row;
        const f16* qr = jb.q + (size_t)row * jb.qstride;
        #pragma unroll
        for (int c = 0; c < KC; c++) qf[t][c] = *(const half8*)(qr + c * 32 + quad * 8);
    }
    floatx4 acc[4][2];
    #pragma unroll
    for (int a = 0; a < 4; a++)
        #pragma unroll
        for (int b = 0; b < 2; b++) acc[a][b] = (floatx4){0.f, 0.f, 0.f, 0.f};

    // B-frag swizzled read offsets (halfs); layout pre-swizzled by convert_w
    int rd_off[2][KC];
    #pragma unroll
    for (int nt = 0; nt < 2; nt++) {
        int nl = wn * 32 + nt * 16 + l15;
        #pragma unroll
        for (int c = 0; c < KC; c++) {
            int g = c * 4 + quad;
            rd_off[nt][c] = nl * M + ((g ^ (nl & GM)) << 3);
        }
    }

    // DMA staging: wave w handles pieces [w*PIECES/4 .. +PIECES/4)
    const int wpBase = wave * (PIECES / 4);
    const f16* wsrc0 = jb.w + (size_t)colBase * M + (size_t)(wpBase + lane) * 8;
    auto stage = [&](int u, int buf) {
        const f16* src = wsrc0 + (size_t)u * SLABFULL;
        f16* dst = &w_lds[buf][0] + (size_t)wpBase * 8;
        #pragma unroll
        for (int i = 0; i < IPW; i++) {
            __builtin_amdgcn_global_load_lds(
                (const __attribute__((address_space(1))) void*)(src + i * 64 * 8),
                (__attribute__((address_space(3))) void*)(dst + i * 64 * 8),
                16, 0, 0);
        }
    };

    stage(0, 0);
    __syncthreads();

    for (int uc = 0; uc < M / 8; uc++) {
        half8 pcur[4];
        #pragma unroll
        for (int t = 0; t < 4; t++)
            pcur[t] = *(const half8*)(jb.p + (size_t)prow[t] * jb.pstride + uc * 8);
        #pragma unroll
        for (int j = 0; j < 8; j++) {
            const int u = uc * 8 + j;
            const int cur = j & 1;           // compile-time slab index
            if (j != 7 || uc != M / 8 - 1) stage(u + 1, cur ^ 1);
            #pragma unroll
            for (int c = 0; c < KC; c++) {
                half8 af[4];
                #pragma unroll
                for (int t = 0; t < 4; t++) {
                    f16 pv = pcur[t][j];
                    half8 p8 = {pv, pv, pv, pv, pv, pv, pv, pv};
                    af[t] = qf[t][c] * p8;    // v_pk_mul_f16
                }
                #pragma unroll
                for (int nt = 0; nt < 2; nt++) {
                    half8 bf = *(const half8*)&w_lds[cur][rd_off[nt][c]];
                    #pragma unroll
                    for (int t = 0; t < 4; t++)
                        acc[t][nt] = __builtin_amdgcn_mfma_f32_16x16x32_f16(af[t], bf, acc[t][nt], 0, 0, 0);
                }
            }
            __syncthreads();
        }
    }
    // epilogue (verified C/D mapping: col=lane&15, row=quad*4+reg)
    #pragma unroll
    for (int t = 0; t < 4; t++)
        #pragma unroll
        for (int nt = 0; nt < 2; nt++) {
            int col = colBase + wn * 32 + nt * 16 + l15;
            float* orow = jb.out + (size_t)(rowBase + wm * 64 + t * 16 + quad * 4) * 128 + col;
            #pragma unroll
            for (int r = 0; r < 4; r++) orow[(size_t)r * 128] = acc[t][nt][r];
        }
}

// ======================= generic small GEMM =======================
// out[b, n] = sum_k A[b,k]*(Amul? Amul[b,k]:1) * W[n*K + k], epilogue modes
struct SmallJob { const f16* A; const f16* W; char* out; int astride; int ostride;
                  int ocol; int cstride; int mode; int Njob; int ny;
                  const f16* Amul; int mstride; };
struct SmallJobs { SmallJob j[4]; };

template <int K>
__launch_bounds__(256, 2)
__global__ void small_gemm(SmallJobs JJ) {
    SmallJob jb = JJ.j[blockIdx.z];
    if ((int)blockIdx.y >= jb.ny) return;
    constexpr int KC = K / 32;
    constexpr int NP = K + 8;
    constexpr int PR = K / 8;
    constexpr int PPT = 128 * K / 8 / 256;
    __shared__ f16 w_lds[128 * NP];
    const int tid = threadIdx.x, lane = tid & 63, wave = tid >> 6;
    const int wm = wave & 1, wn = wave >> 1;
    const int l15 = lane & 15, quad = lane >> 4;
    const int rowBase = blockIdx.x * 128;
    const int nBase = blockIdx.y * 128;

    #pragma unroll
    for (int t = 0; t < PPT; t++) {
        int idx = t * 256 + tid;
        int r = idx / PR, pc = idx % PR;
        int4 v = {0, 0, 0, 0};
        if (nBase + r < jb.Njob)
            v = *(const int4*)(jb.W + (size_t)(nBase + r) * K + pc * 8);
        *(int4*)&w_lds[r * NP + pc * 8] = v;
    }
    half8 qf[4][KC];
    for (int t = 0; t < 4; t++) {
        int row = rowBase + wm * 64 + t * 16 + l15;
        const f16* ar = jb.A + (size_t)row * jb.astride;
        #pragma unroll
        for (int c = 0; c < KC; c++) qf[t][c] = *(const half8*)(ar + c * 32 + quad * 8);
        if (jb.Amul) {
            const f16* mr = jb.Amul + (size_t)row * jb.mstride;
            #pragma unroll
            for (int c = 0; c < KC; c++) qf[t][c] = qf[t][c] * *(const half8*)(mr + c * 32 + quad * 8);
        }
    }
    floatx4 acc[4][4];
    #pragma unroll
    for (int a = 0; a < 4; a++)
        #pragma unroll
        for (int b = 0; b < 4; b++) acc[a][b] = (floatx4){0.f, 0.f, 0.f, 0.f};
    __syncthreads();
    #pragma unroll
    for (int c = 0; c < KC; c++)
        #pragma unroll
        for (int nt = 0; nt < 4; nt++) {
            half8 bf = *(const half8*)&w_lds[(wn * 64 + nt * 16 + l15) * NP + c * 32 + quad * 8];
            #pragma unroll
            for (int t = 0; t < 4; t++)
                acc[t][nt] = __builtin_amdgcn_mfma_f32_16x16x32_f16(qf[t][c], bf, acc[t][nt], 0, 0, 0);
        }
    const float GAIN = 1.5927116870880127f;
    #pragma unroll
    for (int t = 0; t < 4; t++)
        #pragma unroll
        for (int nt = 0; nt < 4; nt++) {
            int col = nBase + wn * 64 + nt * 16 + l15;
            if (col >= jb.Njob) continue;
            int rowB = rowBase + wm * 64 + t * 16 + quad * 4;
            #pragma unroll
            for (int r = 0; r < 4; r++) {
                float v = acc[t][nt][r];
                size_t ro = (size_t)(rowB + r) * jb.ostride;
                if (jb.mode == 0)      ((f16*)jb.out)[ro + jb.ocol + col] = (f16)v;
                else if (jb.mode == 1) ((f16*)jb.out)[ro + jb.ocol + col] = (f16)(GAIN * tanhf(v));
                else                   ((float*)jb.out)[ro + jb.ocol + (size_t)col * jb.cstride] = v;
            }
        }
}

// ======================= elementwise =======================
__global__ void tp_reduce(const float4* __restrict__ P, half4* s_tp, half4* v0, half4* v1, half4* v2) {
    int t = blockIdx.x * 256 + threadIdx.x;
    if (t >= NB * 32) return;
    const size_t S = (size_t)NB * 32;
    float4 a0 = P[t], a1 = P[S + t], a2 = P[2 * S + t], a3 = P[3 * S + t];
    float4 b0 = P[4 * S + t], b1 = P[5 * S + t], b2 = P[6 * S + t];
    float4 c0 = P[7 * S + t], c1 = P[8 * S + t], c2 = P[9 * S + t];
    s_tp[t] = (half4){(f16)(a0.x + a1.x + a2.x + a3.x), (f16)(a0.y + a1.y + a2.y + a3.y),
                      (f16)(a0.z + a1.z + a2.z + a3.z), (f16)(a0.w + a1.w + a2.w + a3.w)};
    v0[t] = (half4){(f16)(b0.x + c0.x), (f16)(b0.y + c0.y), (f16)(b0.z + c0.z), (f16)(b0.w + c0.w)};
    v1[t] = (half4){(f16)(b1.x + c1.x), (f16)(b1.y + c1.y), (f16)(b1.z + c1.z), (f16)(b1.w + c1.w)};
    v2[t] = (half4){(f16)(b2.x + c2.x), (f16)(b2.y + c2.y), (f16)(b2.z + c2.z), (f16)(b2.w + c2.w)};
}

// ======================= host launcher =======================
extern "C" void kernel_launch(void* const* d_in, const int* in_sizes, int n_in,
                              void* d_out, int out_size, void* d_ws, size_t ws_size,
                              hipStream_t stream) {
    const float* x = (const float*)d_in[0];
    const float* W_IN[28];
    for (int i = 0; i < 28; i++) W_IN[i] = (const float*)d_in[1 + i];

    char* base = (char*)d_ws;
    size_t off = 0;
    auto alloc = [&](size_t bytes) -> char* {
        char* p = base + off;
        off += (bytes + 255) & ~(size_t)255;
        return p;
    };
    const size_t S128 = (size_t)NB * 128;

    f16* Wl12_b1_s = (f16*)alloc(8192 * 2);
    f16* Wl12_b1_v = (f16*)alloc(8192 * 2);
    f16* Wl12_b2_s = (f16*)alloc(32768 * 2);
    f16* Wl12_b2_v = (f16*)alloc(32768 * 2);
    f16* Wtp_b1[4]; for (int i = 0; i < 4; i++) Wtp_b1[i] = (f16*)alloc((size_t)64 * 128 * 64 * 2);
    f16* Wtp_b2[4]; for (int i = 0; i < 4; i++) Wtp_b2[i] = (f16*)alloc((size_t)128 * 128 * 128 * 2);
    f16* Wg_b1_sg = (f16*)alloc(32768 * 2);
    f16* Wg_b1_v  = (f16*)alloc(16384 * 2);
    f16* Wg_b2_sg = (f16*)alloc(32768 * 2);
    f16* Wg_b2_v  = (f16*)alloc(16384 * 2);
    f16* Wo_b1_s = (f16*)alloc(16384 * 2);
    f16* Wo_b1_v = (f16*)alloc(16384 * 2);
    f16* Wo_b2_s = (f16*)alloc(16384 * 2);
    f16* Wo_b2_v = (f16*)alloc(16384 * 2);
    f16* Wf_s = (f16*)alloc(8192 * 2);
    f16* Wf_v = (f16*)alloc(8192 * 2);
    f16* s_p = (f16*)alloc((size_t)NB * 64 * 2);
    f16* v_p[3]; for (int i = 0; i < 3; i++) v_p[i] = (f16*)alloc((size_t)NB * 64 * 2);
    f16* Breg = (f16*)alloc((size_t)4 * NB * 256 * 2);
    float* Part = (float*)alloc((size_t)10 * S128 * 4);
    f16* Dreg = (f16*)alloc((size_t)4 * S128 * 2);
    f16* Ereg = (f16*)alloc((size_t)5 * S128 * 2);
    f16* Freg = (f16*)alloc((size_t)4 * S128 * 2);
    (void)ws_size; (void)in_sizes; (void)n_in; (void)out_size;

    const float c_l1 = 0.125f;
    const float c128 = 0.088388347648318447f;
    const float c1 = 1.0f / (64.0f * 1.4142135623730951f);
    const float c2 = 1.0f / (128.0f * 1.4142135623730951f);
    const float i3 = 0.57735026918962584f;

    ConvJobs CJ;
    int jn = 0;
    auto CV = [&](const float* s, f16* d, int K, int N, int uc, float sc, int swz) {
        CJ.j[jn++] = ConvJob{s, d, K, N, uc, sc, swz};
    };
    CV(W_IN[0], Wl12_b1_s, 64, 64, 1, c_l1, 0);  CV(W_IN[2], Wl12_b1_s + 4096, 64, 64, 1, c_l1, 0);
    CV(W_IN[1], Wl12_b1_v, 64, 64, 1, c_l1, 0);  CV(W_IN[3], Wl12_b1_v + 4096, 64, 64, 1, c_l1, 0);
    CV(W_IN[13], Wl12_b2_s, 128, 128, 1, c128, 0); CV(W_IN[15], Wl12_b2_s + 16384, 128, 128, 1, c128, 0);
    CV(W_IN[14], Wl12_b2_v, 128, 128, 1, c128, 0); CV(W_IN[16], Wl12_b2_v + 16384, 128, 128, 1, c128, 0);
    CV(W_IN[4], Wtp_b1[0], 64, 128, 64, c1, 7);  CV(W_IN[5], Wtp_b1[1], 64, 128, 64, c1 * i3, 7);
    CV(W_IN[6], Wtp_b1[2], 64, 128, 64, c1, 7);  CV(W_IN[7], Wtp_b1[3], 64, 128, 64, c1, 7);
    CV(W_IN[17], Wtp_b2[0], 128, 128, 128, c2, 15); CV(W_IN[18], Wtp_b2[1], 128, 128, 128, c2 * i3, 15);
    CV(W_IN[19], Wtp_b2[2], 128, 128, 128, c2, 15); CV(W_IN[20], Wtp_b2[3], 128, 128, 128, c2, 15);
    CV(W_IN[8], Wg_b1_sg, 128, 128, 1, c128, 0);  CV(W_IN[9], Wg_b1_sg + 16384, 128, 128, 1, c128, 0);
    CV(W_IN[10], Wg_b1_v, 128, 128, 1, c128, 0);
    CV(W_IN[21], Wg_b2_sg, 128, 128, 1, c128, 0); CV(W_IN[22], Wg_b2_sg + 16384, 128, 128, 1, c128, 0);
    CV(W_IN[23], Wg_b2_v, 128, 128, 1, c128, 0);
    CV(W_IN[11], Wo_b1_s, 128, 128, 1, c128, 0);  CV(W_IN[12], Wo_b1_v, 128, 128, 1, c128, 0);
    CV(W_IN[24], Wo_b2_s, 128, 128, 1, c128, 0);  CV(W_IN[25], Wo_b2_v, 128, 128, 1, c128, 0);
    CV(W_IN[26], Wf_s, 128, 64, 1, c128, 0);      CV(W_IN[27], Wf_v, 128, 64, 1, c128, 0);
    convert_w<<<dim3(128, 1, 28), 256, 0, stream>>>(CJ);

    x_to_planes<<<NB * 64 / 256, 256, 0, stream>>>(x, s_p, v_p[0], v_p[1], v_p[2]);

    auto SJ = [](const f16* A, const f16* W, void* out, int as, int os, int oc, int cs,
                 int mode, int Nj, int ny, const f16* Amul, int ms) {
        return SmallJob{A, W, (char*)out, as, os, oc, cs, mode, Nj, ny, Amul, ms};
    };

    f16* s12 = Breg;
    f16* v12[3]; for (int i = 0; i < 3; i++) v12[i] = Breg + (size_t)(1 + i) * NB * 128;
    f16* s_tp = Dreg; f16* v_tp[3]; for (int i = 0; i < 3; i++) v_tp[i] = Dreg + (1 + i) * S128;
    f16* sg_gg = Ereg;
    f16* vl[3]; for (int i = 0; i < 3; i++) vl[i] = Ereg + 2 * S128 + i * S128;
    f16* s_o = Freg; f16* v_o[3]; for (int i = 0; i < 3; i++) v_o[i] = Freg + (1 + i) * S128;

    // ---- b1 l1+l2 ----
    {
        SmallJobs J;
        J.j[0] = SJ(s_p, Wl12_b1_s, s12, 64, 128, 0, 1, 0, 128, 1, nullptr, 0);
        for (int i = 0; i < 3; i++) J.j[1 + i] = SJ(v_p[i], Wl12_b1_v, v12[i], 64, 128, 0, 1, 0, 128, 1, nullptr, 0);
        small_gemm<64><<<dim3(64, 1, 4), 256, 0, stream>>>(J);
    }
    // ---- b1 tensor product ----
    {
        TpJobs J;
        J.j[0] = TpJob{s12, s12 + 64, Wtp_b1[0], Part + 0 * S128, 128, 128};
        for (int i = 0; i < 3; i++) J.j[1 + i] = TpJob{v12[i], v12[i] + 64, Wtp_b1[1], Part + (1 + i) * S128, 128, 128};
        for (int i = 0; i < 3; i++) J.j[4 + i] = TpJob{s12, v12[i] + 64, Wtp_b1[2], Part + (4 + i) * S128, 128, 128};
        for (int i = 0; i < 3; i++) J.j[7 + i] = TpJob{v12[i], s12 + 64, Wtp_b1[3], Part + (7 + i) * S128, 128, 128};
        tp_unit<64><<<dim3(64, 2, 10), 256, 0, stream>>>(J);
    }
    tp_reduce<<<NB * 32 / 256, 256, 0, stream>>>((const float4*)Part, (half4*)s_tp, (half4*)v_tp[0], (half4*)v_tp[1], (half4*)v_tp[2]);
    // ---- b1 gate ----
    {
        SmallJobs J;
        J.j[0] = SJ(s_tp, Wg_b1_sg, sg_gg, 128, 256, 0, 1, 1, 256, 2, nullptr, 0);
        for (int i = 0; i < 3; i++) J.j[1 + i] = SJ(v_tp[i], Wg_b1_v, vl[i], 128, 128, 0, 1, 0, 128, 1, nullptr, 0);
        small_gemm<128><<<dim3(64, 2, 4), 256, 0, stream>>>(J);
    }
    // ---- b1 o-lin (vgate fused via Amul) ----
    {
        SmallJobs J;
        J.j[0] = SJ(sg_gg, Wo_b1_s, s_o, 256, 128, 0, 1, 0, 128, 1, nullptr, 0);
        for (int i = 0; i < 3; i++) J.j[1 + i] = SJ(vl[i], Wo_b1_v, v_o[i], 128, 128, 0, 1, 0, 128, 1, sg_gg + 128, 256);
        small_gemm<128><<<dim3(64, 1, 4), 256, 0, stream>>>(J);
    }
    f16* s12b = Breg;
    f16* v12b[3]; for (int i = 0; i < 3; i++) v12b[i] = Breg + (size_t)(1 + i) * NB * 256;
    // ---- b2 l1+l2 ----
    {
        SmallJobs J;
        J.j[0] = SJ(s_o, Wl12_b2_s, s12b, 128, 256, 0, 1, 0, 256, 2, nullptr, 0);
        for (int i = 0; i < 3; i++) J.j[1 + i] = SJ(v_o[i], Wl12_b2_v, v12b[i], 128, 256, 0, 1, 0, 256, 2, nullptr, 0);
        small_gemm<128><<<dim3(64, 2, 4), 256, 0, stream>>>(J);
    }
    // ---- b2 tensor product ----
    {
        TpJobs J;
        J.j[0] = TpJob{s12b, s12b + 128, Wtp_b2[0], Part + 0 * S128, 256, 256};
        for (int i = 0; i < 3; i++) J.j[1 + i] = TpJob{v12b[i], v12b[i] + 128, Wtp_b2[1], Part + (1 + i) * S128, 256, 256};
        for (int i = 0; i < 3; i++) J.j[4 + i] = TpJob{s12b, v12b[i] + 128, Wtp_b2[2], Part + (4 + i) * S128, 256, 256};
        for (int i = 0; i < 3; i++) J.j[7 + i] = TpJob{v12b[i], s12b + 128, Wtp_b2[3], Part + (7 + i) * S128, 256, 256};
        tp_unit<128><<<dim3(64, 2, 10), 256, 0, stream>>>(J);
    }
    tp_reduce<<<NB * 32 / 256, 256, 0, stream>>>((const float4*)Part, (half4*)s_tp, (half4*)v_tp[0], (half4*)v_tp[1], (half4*)v_tp[2]);
    // ---- b2 gate ----
    {
        SmallJobs J;
        J.j[0] = SJ(s_tp, Wg_b2_sg, sg_gg, 128, 256, 0, 1, 1, 256, 2, nullptr, 0);
        for (int i = 0; i < 3; i++) J.j[1 + i] = SJ(v_tp[i], Wg_b2_v, vl[i], 128, 128, 0, 1, 0, 128, 1, nullptr, 0);
        small_gemm<128><<<dim3(64, 2, 4), 256, 0, stream>>>(J);
    }
    // ---- b2 o-lin (vgate fused) ----
    {
        SmallJobs J;
        J.j[0] = SJ(sg_gg, Wo_b2_s, s_o, 256, 128, 0, 1, 0, 128, 1, nullptr, 0);
        for (int i = 0; i < 3; i++) J.j[1 + i] = SJ(vl[i], Wo_b2_v, v_o[i], 128, 128, 0, 1, 0, 128, 1, sg_gg + 128, 256);
        small_gemm<128><<<dim3(64, 1, 4), 256, 0, stream>>>(J);
    }
    // ---- final lin -> d_out ----
    {
        SmallJobs J;
        J.j[0] = SJ(s_o, Wf_s, d_out, 128, 256, 0, 1, 2, 64, 1, nullptr, 0);
        for (int i = 0; i < 3; i++) J.j[1 + i] = SJ(v_o[i], Wf_v, d_out, 128, 256, 64 + i, 3, 2, 64, 1, nullptr, 0);
        small_gemm<128><<<dim3(64, 1, 4), 256, 0, stream>>>(J);
    }
}

// Round 7
// 624.381 us; speedup vs baseline: 2.8149x; 2.8149x over previous
//
#include <hip/hip_runtime.h>
#include <math.h>

typedef _Float16 f16;
typedef __attribute__((ext_vector_type(8))) _Float16 half8;
typedef __attribute__((ext_vector_type(4))) _Float16 half4;
typedef __attribute__((ext_vector_type(4))) float floatx4;

#define NB 8192

// ======================= weight conversion =======================
// Linear (swz==0): dst[u][n][k] = src[u*K*N + k*N + n] * scale
// Swizzled (swz==GM): dst piece (n, g') holds k-group g = g'^(n&swz), so that a
// linear lane-order global_load_lds lands XOR-swizzled data in LDS.
struct ConvJob { const float* src; f16* dst; int K; int N; int ucount; float scale; int swz; };
struct ConvJobs { ConvJob j[28]; };

__global__ void convert_w(ConvJobs JJ) {
    ConvJob jb = JJ.j[blockIdx.z];
    int u = blockIdx.x;
    if (u >= jb.ucount) return;
    __shared__ f16 tile[128 * 136];
    const int K = jb.K, N = jb.N;
    const int npad = N + 8;
    const int nsh = (N == 128) ? 7 : 6;
    const int ksh = (K == 128) ? 7 : 6;
    const float* src = jb.src + (size_t)u * K * N;
    for (int idx = threadIdx.x; idx < K * N; idx += 256) {
        int k = idx >> nsh, n = idx & (N - 1);
        tile[k * npad + n] = (f16)(src[idx] * jb.scale);
    }
    __syncthreads();
    f16* dst = jb.dst + (size_t)u * N * K;
    for (int idx = threadIdx.x; idx < N * K; idx += 256) {
        int n = idx >> ksh, rem = idx & (K - 1);
        int g2 = rem >> 3, jj = rem & 7;
        int g = jb.swz ? (g2 ^ (n & jb.swz)) : g2;
        int k = g * 8 + jj;
        dst[idx] = tile[k * npad + n];
    }
}

// ======================= x -> planar f16 =======================
__global__ void x_to_planes(const float* __restrict__ x, f16* s_p, f16* v0, f16* v1, f16* v2) {
    int t = blockIdx.x * 256 + threadIdx.x;
    if (t >= NB * 64) return;
    int b = t >> 6, u = t & 63;
    const float* xr = x + (size_t)b * 256;
    s_p[t] = (f16)xr[u];
    v0[t] = (f16)xr[64 + 3 * u + 0];
    v1[t] = (f16)xr[64 + 3 * u + 1];
    v2[t] = (f16)xr[64 + 3 * u + 2];
}

// ======================= tensor-product unit (round-3 proven version) =======================
// out[b,w] = sum_u p[b,u] * sum_v q[b,v] * Wt[u][w][v]
// W staged global->LDS via global_load_lds (no VGPR round-trip); pre-swizzled so
// linear DMA lands conflict-free; 2-slab LDS + one __syncthreads per u-step with
// compile-time slab index. Bound 3: VGPR cap ~85 (measured 84, no spill) — the
// residency optimum; bound 5 caused scratch spill (r6), bound 4 would cap at 64.
struct TpJob { const f16* p; const f16* q; const f16* w; float* out; int pstride; int qstride; };
struct TpJobs { TpJob j[10]; };

template <int M>
__launch_bounds__(256, (M == 128) ? 3 : 4)
__global__ void tp_unit(TpJobs JJ) {
    TpJob jb = JJ.j[blockIdx.z];
    constexpr int KC = M / 32;            // 32-wide k chunks
    constexpr int GM = M / 8 - 1;         // swizzle key mask
    constexpr int SLABH = 64 * M;         // halfs per col-half slab
    constexpr int PIECES = SLABH / 8;     // 16B pieces per slab
    constexpr int IPW = PIECES / 256;     // glds instrs per thread per stage
    constexpr int SLABFULL = 128 * M;     // halfs per full (128-col) slab
    __shared__ f16 w_lds[2][SLABH];
    const int tid = threadIdx.x, lane = tid & 63, wave = tid >> 6;
    const int wm = wave & 1, wn = wave >> 1;
    const int l15 = lane & 15, quad = lane >> 4;
    const int rowBase = blockIdx.x * 128;
    const int colBase = blockIdx.y * 64;

    // Q fragments: register-resident (A-operand source)
    half8 qf[4][KC];
    int prow[4];
    #pragma unroll
    for (int t = 0; t < 4; t++) {
        int row = rowBase + wm * 64 + t * 16 + l15;
        prow[t] = row;
        const f16* qr = jb.q + (size_t)row * jb.qstride;
        #pragma unroll
        for (int c = 0; c < KC; c++) qf[t][c] = *(const half8*)(qr + c * 32 + quad * 8);
    }
    floatx4 acc[4][2];
    #pragma unroll
    for (int a = 0; a < 4; a++)
        #pragma unroll
        for (int b = 0; b < 2; b++) acc[a][b] = (floatx4){0.f, 0.f, 0.f, 0.f};

    // B-frag swizzled read offsets (halfs); layout pre-swizzled by convert_w
    int rd_off[2][KC];
    #pragma unroll
    for (int nt = 0; nt < 2; nt++) {
        int nl = wn * 32 + nt * 16 + l15;
        #pragma unroll
        for (int c = 0; c < KC; c++) {
            int g = c * 4 + quad;
            rd_off[nt][c] = nl * M + ((g ^ (nl & GM)) << 3);
        }
    }

    // DMA staging: wave w handles pieces [w*PIECES/4 .. +PIECES/4)
    const int wpBase = wave * (PIECES / 4);
    const f16* wsrc0 = jb.w + (size_t)colBase * M + (size_t)(wpBase + lane) * 8;
    auto stage = [&](int u, int buf) {
        const f16* src = wsrc0 + (size_t)u * SLABFULL;
        f16* dst = &w_lds[buf][0] + (size_t)wpBase * 8;
        #pragma unroll
        for (int i = 0; i < IPW; i++) {
            __builtin_amdgcn_global_load_lds(
                (const __attribute__((address_space(1))) void*)(src + i * 64 * 8),
                (__attribute__((address_space(3))) void*)(dst + i * 64 * 8),
                16, 0, 0);
        }
    };

    stage(0, 0);
    __syncthreads();

    for (int uc = 0; uc < M / 8; uc++) {
        half8 pcur[4];
        #pragma unroll
        for (int t = 0; t < 4; t++)
            pcur[t] = *(const half8*)(jb.p + (size_t)prow[t] * jb.pstride + uc * 8);
        #pragma unroll
        for (int j = 0; j < 8; j++) {
            const int u = uc * 8 + j;
            const int cur = j & 1;           // compile-time slab index
            if (j != 7 || uc != M / 8 - 1) stage(u + 1, cur ^ 1);
            #pragma unroll
            for (int c = 0; c < KC; c++) {
                half8 af[4];
                #pragma unroll
                for (int t = 0; t < 4; t++) {
                    f16 pv = pcur[t][j];
                    half8 p8 = {pv, pv, pv, pv, pv, pv, pv, pv};
                    af[t] = qf[t][c] * p8;    // v_pk_mul_f16
                }
                #pragma unroll
                for (int nt = 0; nt < 2; nt++) {
                    half8 bf = *(const half8*)&w_lds[cur][rd_off[nt][c]];
                    #pragma unroll
                    for (int t = 0; t < 4; t++)
                        acc[t][nt] = __builtin_amdgcn_mfma_f32_16x16x32_f16(af[t], bf, acc[t][nt], 0, 0, 0);
                }
            }
            __syncthreads();
        }
    }
    // epilogue (verified C/D mapping: col=lane&15, row=quad*4+reg)
    #pragma unroll
    for (int t = 0; t < 4; t++)
        #pragma unroll
        for (int nt = 0; nt < 2; nt++) {
            int col = colBase + wn * 32 + nt * 16 + l15;
            float* orow = jb.out + (size_t)(rowBase + wm * 64 + t * 16 + quad * 4) * 128 + col;
            #pragma unroll
            for (int r = 0; r < 4; r++) orow[(size_t)r * 128] = acc[t][nt][r];
        }
}

// ======================= generic small GEMM (64-row blocks) =======================
// out[b, n] = sum_k A[b,k]*(Amul? Amul[b,k]:1) * W[n*K + k], epilogue modes.
// If nred>0: A[b,k] = f16( sum_i red_i[b*128 + k] )  (f32 planes, stride 128)
struct SmallJob { const f16* A; const f16* W; char* out; int astride; int ostride;
                  int ocol; int cstride; int mode; int Njob; int ny;
                  const f16* Amul; int mstride;
                  const float* red0; const float* red1; const float* red2; const float* red3;
                  int nred; };
struct SmallJobs { SmallJob j[4]; };

template <int K>
__launch_bounds__(256, 2)
__global__ void small_gemm(SmallJobs JJ) {
    SmallJob jb = JJ.j[blockIdx.z];
    if ((int)blockIdx.y >= jb.ny) return;
    constexpr int KC = K / 32;
    constexpr int NP = K + 8;
    constexpr int PR = K / 8;
    constexpr int PPT = 128 * K / 8 / 256;
    __shared__ f16 w_lds[128 * NP];
    const int tid = threadIdx.x, lane = tid & 63, wave = tid >> 6;
    const int wm = wave & 1, wn = wave >> 1;
    const int l15 = lane & 15, quad = lane >> 4;
    const int rowBase = blockIdx.x * 64;     // 64-row blocks for CU coverage
    const int nBase = blockIdx.y * 128;

    #pragma unroll
    for (int t = 0; t < PPT; t++) {
        int idx = t * 256 + tid;
        int r = idx / PR, pc = idx % PR;
        int4 v = {0, 0, 0, 0};
        if (nBase + r < jb.Njob)
            v = *(const int4*)(jb.W + (size_t)(nBase + r) * K + pc * 8);
        *(int4*)&w_lds[r * NP + pc * 8] = v;
    }
    half8 qf[2][KC];
    for (int t = 0; t < 2; t++) {
        int row = rowBase + wm * 32 + t * 16 + l15;
        if (jb.nred) {
            #pragma unroll
            for (int c = 0; c < KC; c++) {
                size_t boff = (size_t)row * 128 + c * 32 + quad * 8;
                floatx4 s0 = *(const floatx4*)(jb.red0 + boff);
                floatx4 s1 = *(const floatx4*)(jb.red0 + boff + 4);
                if (jb.nred > 1) { s0 += *(const floatx4*)(jb.red1 + boff); s1 += *(const floatx4*)(jb.red1 + boff + 4); }
                if (jb.nred > 2) { s0 += *(const floatx4*)(jb.red2 + boff); s1 += *(const floatx4*)(jb.red2 + boff + 4); }
                if (jb.nred > 3) { s0 += *(const floatx4*)(jb.red3 + boff); s1 += *(const floatx4*)(jb.red3 + boff + 4); }
                qf[t][c] = (half8){(f16)s0.x, (f16)s0.y, (f16)s0.z, (f16)s0.w,
                                   (f16)s1.x, (f16)s1.y, (f16)s1.z, (f16)s1.w};
            }
        } else {
            const f16* ar = jb.A + (size_t)row * jb.astride;
            #pragma unroll
            for (int c = 0; c < KC; c++) qf[t][c] = *(const half8*)(ar + c * 32 + quad * 8);
        }
        if (jb.Amul) {
            const f16* mr = jb.Amul + (size_t)row * jb.mstride;
            #pragma unroll
            for (int c = 0; c < KC; c++) qf[t][c] = qf[t][c] * *(const half8*)(mr + c * 32 + quad * 8);
        }
    }
    floatx4 acc[2][4];
    #pragma unroll
    for (int a = 0; a < 2; a++)
        #pragma unroll
        for (int b = 0; b < 4; b++) acc[a][b] = (floatx4){0.f, 0.f, 0.f, 0.f};
    __syncthreads();
    #pragma unroll
    for (int c = 0; c < KC; c++)
        #pragma unroll
        for (int nt = 0; nt < 4; nt++) {
            half8 bf = *(const half8*)&w_lds[(wn * 64 + nt * 16 + l15) * NP + c * 32 + quad * 8];
            #pragma unroll
            for (int t = 0; t < 2; t++)
                acc[t][nt] = __builtin_amdgcn_mfma_f32_16x16x32_f16(qf[t][c], bf, acc[t][nt], 0, 0, 0);
        }
    const float GAIN = 1.5927116870880127f;
    #pragma unroll
    for (int t = 0; t < 2; t++)
        #pragma unroll
        for (int nt = 0; nt < 4; nt++) {
            int col = nBase + wn * 64 + nt * 16 + l15;
            if (col >= jb.Njob) continue;
            int rowB = rowBase + wm * 32 + t * 16 + quad * 4;
            #pragma unroll
            for (int r = 0; r < 4; r++) {
                float v = acc[t][nt][r];
                size_t ro = (size_t)(rowB + r) * jb.ostride;
                if (jb.mode == 0)      ((f16*)jb.out)[ro + jb.ocol + col] = (f16)v;
                else if (jb.mode == 1) ((f16*)jb.out)[ro + jb.ocol + col] = (f16)(GAIN * tanhf(v));
                else                   ((float*)jb.out)[ro + jb.ocol + (size_t)col * jb.cstride] = v;
            }
        }
}

// ======================= host launcher =======================
extern "C" void kernel_launch(void* const* d_in, const int* in_sizes, int n_in,
                              void* d_out, int out_size, void* d_ws, size_t ws_size,
                              hipStream_t stream) {
    const float* x = (const float*)d_in[0];
    const float* W_IN[28];
    for (int i = 0; i < 28; i++) W_IN[i] = (const float*)d_in[1 + i];

    char* base = (char*)d_ws;
    size_t off = 0;
    auto alloc = [&](size_t bytes) -> char* {
        char* p = base + off;
        off += (bytes + 255) & ~(size_t)255;
        return p;
    };
    const size_t S128 = (size_t)NB * 128;

    f16* Wl12_b1_s = (f16*)alloc(8192 * 2);
    f16* Wl12_b1_v = (f16*)alloc(8192 * 2);
    f16* Wl12_b2_s = (f16*)alloc(32768 * 2);
    f16* Wl12_b2_v = (f16*)alloc(32768 * 2);
    f16* Wtp_b1[4]; for (int i = 0; i < 4; i++) Wtp_b1[i] = (f16*)alloc((size_t)64 * 128 * 64 * 2);
    f16* Wtp_b2[4]; for (int i = 0; i < 4; i++) Wtp_b2[i] = (f16*)alloc((size_t)128 * 128 * 128 * 2);
    f16* Wg_b1_sg = (f16*)alloc(32768 * 2);
    f16* Wg_b1_v  = (f16*)alloc(16384 * 2);
    f16* Wg_b2_sg = (f16*)alloc(32768 * 2);
    f16* Wg_b2_v  = (f16*)alloc(16384 * 2);
    f16* Wo_b1_s = (f16*)alloc(16384 * 2);
    f16* Wo_b1_v = (f16*)alloc(16384 * 2);
    f16* Wo_b2_s = (f16*)alloc(16384 * 2);
    f16* Wo_b2_v = (f16*)alloc(16384 * 2);
    f16* Wf_s = (f16*)alloc(8192 * 2);
    f16* Wf_v = (f16*)alloc(8192 * 2);
    f16* s_p = (f16*)alloc((size_t)NB * 64 * 2);
    f16* v_p[3]; for (int i = 0; i < 3; i++) v_p[i] = (f16*)alloc((size_t)NB * 64 * 2);
    f16* Breg = (f16*)alloc((size_t)4 * NB * 256 * 2);
    float* Part = (float*)alloc((size_t)10 * S128 * 4);
    f16* Ereg = (f16*)alloc((size_t)5 * S128 * 2);
    f16* Freg = (f16*)alloc((size_t)4 * S128 * 2);
    (void)ws_size; (void)in_sizes; (void)n_in; (void)out_size;

    const float c_l1 = 0.125f;
    const float c128 = 0.088388347648318447f;
    const float c1 = 1.0f / (64.0f * 1.4142135623730951f);
    const float c2 = 1.0f / (128.0f * 1.4142135623730951f);
    const float i3 = 0.57735026918962584f;

    ConvJobs CJ;
    int jn = 0;
    auto CV = [&](const float* s, f16* d, int K, int N, int uc, float sc, int swz) {
        CJ.j[jn++] = ConvJob{s, d, K, N, uc, sc, swz};
    };
    CV(W_IN[0], Wl12_b1_s, 64, 64, 1, c_l1, 0);  CV(W_IN[2], Wl12_b1_s + 4096, 64, 64, 1, c_l1, 0);
    CV(W_IN[1], Wl12_b1_v, 64, 64, 1, c_l1, 0);  CV(W_IN[3], Wl12_b1_v + 4096, 64, 64, 1, c_l1, 0);
    CV(W_IN[13], Wl12_b2_s, 128, 128, 1, c128, 0); CV(W_IN[15], Wl12_b2_s + 16384, 128, 128, 1, c128, 0);
    CV(W_IN[14], Wl12_b2_v, 128, 128, 1, c128, 0); CV(W_IN[16], Wl12_b2_v + 16384, 128, 128, 1, c128, 0);
    CV(W_IN[4], Wtp_b1[0], 64, 128, 64, c1, 7);  CV(W_IN[5], Wtp_b1[1], 64, 128, 64, c1 * i3, 7);
    CV(W_IN[6], Wtp_b1[2], 64, 128, 64, c1, 7);  CV(W_IN[7], Wtp_b1[3], 64, 128, 64, c1, 7);
    CV(W_IN[17], Wtp_b2[0], 128, 128, 128, c2, 15); CV(W_IN[18], Wtp_b2[1], 128, 128, 128, c2 * i3, 15);
    CV(W_IN[19], Wtp_b2[2], 128, 128, 128, c2, 15); CV(W_IN[20], Wtp_b2[3], 128, 128, 128, c2, 15);
    CV(W_IN[8], Wg_b1_sg, 128, 128, 1, c128, 0);  CV(W_IN[9], Wg_b1_sg + 16384, 128, 128, 1, c128, 0);
    CV(W_IN[10], Wg_b1_v, 128, 128, 1, c128, 0);
    CV(W_IN[21], Wg_b2_sg, 128, 128, 1, c128, 0); CV(W_IN[22], Wg_b2_sg + 16384, 128, 128, 1, c128, 0);
    CV(W_IN[23], Wg_b2_v, 128, 128, 1, c128, 0);
    CV(W_IN[11], Wo_b1_s, 128, 128, 1, c128, 0);  CV(W_IN[12], Wo_b1_v, 128, 128, 1, c128, 0);
    CV(W_IN[24], Wo_b2_s, 128, 128, 1, c128, 0);  CV(W_IN[25], Wo_b2_v, 128, 128, 1, c128, 0);
    CV(W_IN[26], Wf_s, 128, 64, 1, c128, 0);      CV(W_IN[27], Wf_v, 128, 64, 1, c128, 0);
    convert_w<<<dim3(128, 1, 28), 256, 0, stream>>>(CJ);

    x_to_planes<<<NB * 64 / 256, 256, 0, stream>>>(x, s_p, v_p[0], v_p[1], v_p[2]);

    auto SJ = [](const f16* A, const f16* W, void* out, int as, int os, int oc, int cs,
                 int mode, int Nj, int ny, const f16* Amul, int ms) {
        return SmallJob{A, W, (char*)out, as, os, oc, cs, mode, Nj, ny, Amul, ms,
                        nullptr, nullptr, nullptr, nullptr, 0};
    };

    f16* s12 = Breg;
    f16* v12[3]; for (int i = 0; i < 3; i++) v12[i] = Breg + (size_t)(1 + i) * NB * 128;
    f16* sg_gg = Ereg;
    f16* vl[3]; for (int i = 0; i < 3; i++) vl[i] = Ereg + 2 * S128 + i * S128;
    f16* s_o = Freg; f16* v_o[3]; for (int i = 0; i < 3; i++) v_o[i] = Freg + (1 + i) * S128;

    // ---- b1 l1+l2 ----
    {
        SmallJobs J;
        J.j[0] = SJ(s_p, Wl12_b1_s, s12, 64, 128, 0, 1, 0, 128, 1, nullptr, 0);
        for (int i = 0; i < 3; i++) J.j[1 + i] = SJ(v_p[i], Wl12_b1_v, v12[i], 64, 128, 0, 1, 0, 128, 1, nullptr, 0);
        small_gemm<64><<<dim3(128, 1, 4), 256, 0, stream>>>(J);
    }
    // ---- b1 tensor product ----
    {
        TpJobs J;
        J.j[0] = TpJob{s12, s12 + 64, Wtp_b1[0], Part + 0 * S128, 128, 128};
        for (int i = 0; i < 3; i++) J.j[1 + i] = TpJob{v12[i], v12[i] + 64, Wtp_b1[1], Part + (1 + i) * S128, 128, 128};
        for (int i = 0; i < 3; i++) J.j[4 + i] = TpJob{s12, v12[i] + 64, Wtp_b1[2], Part + (4 + i) * S128, 128, 128};
        for (int i = 0; i < 3; i++) J.j[7 + i] = TpJob{v12[i], s12 + 64, Wtp_b1[3], Part + (7 + i) * S128, 128, 128};
        tp_unit<64><<<dim3(64, 2, 10), 256, 0, stream>>>(J);
    }
    // ---- b1 gate (tp_reduce fused into A-load) ----
    {
        SmallJobs J;
        J.j[0] = SmallJob{nullptr, Wg_b1_sg, (char*)sg_gg, 128, 256, 0, 1, 1, 256, 2, nullptr, 0,
                          Part + 0 * S128, Part + 1 * S128, Part + 2 * S128, Part + 3 * S128, 4};
        for (int i = 0; i < 3; i++)
            J.j[1 + i] = SmallJob{nullptr, Wg_b1_v, (char*)vl[i], 128, 128, 0, 1, 0, 128, 1, nullptr, 0,
                                  Part + (4 + i) * S128, Part + (7 + i) * S128, nullptr, nullptr, 2};
        small_gemm<128><<<dim3(128, 2, 4), 256, 0, stream>>>(J);
    }
    // ---- b1 o-lin (vgate fused via Amul) ----
    {
        SmallJobs J;
        J.j[0] = SJ(sg_gg, Wo_b1_s, s_o, 256, 128, 0, 1, 0, 128, 1, nullptr, 0);
        for (int i = 0; i < 3; i++) J.j[1 + i] = SJ(vl[i], Wo_b1_v, v_o[i], 128, 128, 0, 1, 0, 128, 1, sg_gg + 128, 256);
        small_gemm<128><<<dim3(128, 1, 4), 256, 0, stream>>>(J);
    }
    f16* s12b = Breg;
    f16* v12b[3]; for (int i = 0; i < 3; i++) v12b[i] = Breg + (size_t)(1 + i) * NB * 256;
    // ---- b2 l1+l2 ----
    {
        SmallJobs J;
        J.j[0] = SJ(s_o, Wl12_b2_s, s12b, 128, 256, 0, 1, 0, 256, 2, nullptr, 0);
        for (int i = 0; i < 3; i++) J.j[1 + i] = SJ(v_o[i], Wl12_b2_v, v12b[i], 128, 256, 0, 1, 0, 256, 2, nullptr, 0);
        small_gemm<128><<<dim3(128, 2, 4), 256, 0, stream>>>(J);
    }
    // ---- b2 tensor product ----
    {
        TpJobs J;
        J.j[0] = TpJob{s12b, s12b + 128, Wtp_b2[0], Part + 0 * S128, 256, 256};
        for (int i = 0; i < 3; i++) J.j[1 + i] = TpJob{v12b[i], v12b[i] + 128, Wtp_b2[1], Part + (1 + i) * S128, 256, 256};
        for (int i = 0; i < 3; i++) J.j[4 + i] = TpJob{s12b, v12b[i] + 128, Wtp_b2[2], Part + (4 + i) * S128, 256, 256};
        for (int i = 0; i < 3; i++) J.j[7 + i] = TpJob{v12b[i], s12b + 128, Wtp_b2[3], Part + (7 + i) * S128, 256, 256};
        tp_unit<128><<<dim3(64, 2, 10), 256, 0, stream>>>(J);
    }
    // ---- b2 gate (tp_reduce fused) ----
    {
        SmallJobs J;
        J.j[0] = SmallJob{nullptr, Wg_b2_sg, (char*)sg_gg, 128, 256, 0, 1, 1, 256, 2, nullptr, 0,
                          Part + 0 * S128, Part + 1 * S128, Part + 2 * S128, Part + 3 * S128, 4};
        for (int i = 0; i < 3; i++)
            J.j[1 + i] = SmallJob{nullptr, Wg_b2_v, (char*)vl[i], 128, 128, 0, 1, 0, 128, 1, nullptr, 0,
                                  Part + (4 + i) * S128, Part + (7 + i) * S128, nullptr, nullptr, 2};
        small_gemm<128><<<dim3(128, 2, 4), 256, 0, stream>>>(J);
    }
    // ---- b2 o-lin (vgate fused) ----
    {
        SmallJobs J;
        J.j[0] = SJ(sg_gg, Wo_b2_s, s_o, 256, 128, 0, 1, 0, 128, 1, nullptr, 0);
        for (int i = 0; i < 3; i++) J.j[1 + i] = SJ(vl[i], Wo_b2_v, v_o[i], 128, 128, 0, 1, 0, 128, 1, sg_gg + 128, 256);
        small_gemm<128><<<dim3(128, 1, 4), 256, 0, stream>>>(J);
    }
    // ---- final lin -> d_out ----
    {
        SmallJobs J;
        J.j[0] = SJ(s_o, Wf_s, d_out, 128, 256, 0, 1, 2, 64, 1, nullptr, 0);
        for (int i = 0; i < 3; i++) J.j[1 + i] = SJ(v_o[i], Wf_v, d_out, 128, 256, 64 + i, 3, 2, 64, 1, nullptr, 0);
        small_gemm<128><<<dim3(128, 1, 4), 256, 0, stream>>>(J);
    }
}